// Round 14
// baseline (5643.871 us; speedup 1.0000x reference)
//
#include <hip/hip_runtime.h>
#include <hip/hip_bf16.h>
#include <stdint.h>

#define DIMD 1024
#define NSEQ 4096
#define BATCH 8
#define LN_EPS 1e-5f

typedef __attribute__((ext_vector_type(8))) short bf16x8;
typedef __attribute__((ext_vector_type(4))) float f32x4;

__device__ __forceinline__ ushort f2bf(float f) {
  union { __hip_bfloat16 h; ushort u; } cv;
  cv.h = __float2bfloat16(f);
  return cv.u;
}

__device__ __forceinline__ float fexp2(float x) {
  return exp2f(x);   // maps to v_exp_f32
}

__device__ __forceinline__ void gload16(const void* g, void* l) {
  __builtin_amdgcn_global_load_lds(
      (const __attribute__((address_space(1))) uint32_t*)g,
      (__attribute__((address_space(3))) uint32_t*)l, 16, 0, 0);
}

#define MIDBAR()   asm volatile("s_barrier" ::: "memory")
#define ENDBAR()   asm volatile("s_waitcnt lgkmcnt(0)\n\ts_barrier" ::: "memory")
#define ENDBARV0() asm volatile("s_waitcnt vmcnt(0) lgkmcnt(0)\n\ts_barrier" ::: "memory")

// LDS XOR swizzle (involution). Verified round 5: SQ_LDS_BANK_CONFLICT == 0.
__device__ __forceinline__ int swz64(int byte) {
  return byte ^ (((byte >> 7) & 3) << 4);
}

// ---------------- LayerNorm (fp32 in -> bf16 out, scale folded) -------------
__global__ __launch_bounds__(256) void ln_bf16_kernel(
    const float* __restrict__ x, const float* __restrict__ gamma,
    const float* __restrict__ beta, ushort* __restrict__ y, float scale)
{
  const int lane = threadIdx.x & 63;
  const int wv   = threadIdx.x >> 6;
  const size_t row = (size_t)blockIdx.x * 4 + wv;
  const float* xr = x + row * DIMD;

  float4 v[4];
#pragma unroll
  for (int c = 0; c < 4; ++c)
    v[c] = *(const float4*)(xr + c * 256 + lane * 4);

  float s = 0.f;
#pragma unroll
  for (int c = 0; c < 4; ++c) s += v[c].x + v[c].y + v[c].z + v[c].w;
#pragma unroll
  for (int m = 32; m >= 1; m >>= 1) s += __shfl_xor(s, m, 64);
  const float mean = s * (1.0f / DIMD);

  float vs = 0.f;
#pragma unroll
  for (int c = 0; c < 4; ++c) {
    float a0 = v[c].x - mean, a1 = v[c].y - mean;
    float a2 = v[c].z - mean, a3 = v[c].w - mean;
    vs += a0 * a0 + a1 * a1 + a2 * a2 + a3 * a3;
  }
#pragma unroll
  for (int m = 32; m >= 1; m >>= 1) vs += __shfl_xor(vs, m, 64);
  const float rstd = rsqrtf(vs * (1.0f / DIMD) + LN_EPS);

  ushort* yr = y + row * DIMD;
#pragma unroll
  for (int c = 0; c < 4; ++c) {
    const int d = c * 256 + lane * 4;
    float4 g  = *(const float4*)(gamma + d);
    float4 bb = *(const float4*)(beta + d);
    ushort4 o;
    o.x = f2bf(((v[c].x - mean) * rstd * g.x + bb.x) * scale);
    o.y = f2bf(((v[c].y - mean) * rstd * g.y + bb.y) * scale);
    o.z = f2bf(((v[c].z - mean) * rstd * g.z + bb.z) * scale);
    o.w = f2bf(((v[c].w - mean) * rstd * g.w + bb.w) * scale);
    *(ushort4*)(yr + d) = o;
  }
}

// ---------------- bf16 transpose: [b][n][d] -> [b][d][n] --------------------
__global__ __launch_bounds__(256) void transpose_kernel(
    const ushort* __restrict__ src, ushort* __restrict__ dst)
{
  __shared__ ushort tile[64][72];
  const int t   = threadIdx.x;
  const int bid = blockIdx.x;
  const int b   = bid >> 10;
  const int rem = bid & 1023;
  const int n0  = (rem >> 4) << 6;
  const int d0  = (rem & 15) << 6;
  const ushort* sb = src + ((size_t)b * NSEQ) * DIMD;
  ushort* db       = dst + ((size_t)b * DIMD) * NSEQ;

#pragma unroll
  for (int k = 0; k < 2; ++k) {
    int c = t + 256 * k;
    int r = c >> 3, scol = (c & 7) * 8;
    *(uint4*)&tile[r][scol] =
        *(const uint4*)(sb + (size_t)(n0 + r) * DIMD + d0 + scol);
  }
  __syncthreads();
#pragma unroll
  for (int k = 0; k < 2; ++k) {
    int c = t + 256 * k;
    int dr = c >> 3, ns = (c & 7) * 8;
    union { ushort u[8]; uint4 q; } tv;
#pragma unroll
    for (int i = 0; i < 8; ++i) tv.u[i] = tile[ns + i][dr];
    *(uint4*)(db + (size_t)(d0 + dr) * NSEQ + n0 + ns) = tv.q;
  }
}

// ================== shared GEMM building blocks =============================
// chunk = [256 rows][32 k-cols] bf16 = 16KB, swz64-swizzled image.
__device__ __forceinline__ void stage_chunk(const ushort* __restrict__ g,
                                            int ld, char* l, int tid) {
  const int o0 = tid * 16;
  const int o1 = o0 + 8192;
  const int s0 = swz64(o0);
  const int s1 = swz64(o1);
  gload16(g + (size_t)(s0 >> 6) * ld + ((s0 & 63) >> 1), l + o0);
  gload16(g + (size_t)(s1 >> 6) * ld + ((s1 & 63) >> 1), l + o1);
}

// linear stage: global already holds the swizzled 16KB chunk image
__device__ __forceinline__ void stage_lin(const ushort* __restrict__ g,
                                          char* l, int tid) {
  gload16(g + tid * 8,        l + tid * 16);
  gload16(g + 4096 + tid * 8, l + tid * 16 + 8192);
}

__device__ __forceinline__ bf16x8 ldsw_read(const char* base, int row, int lg) {
  return *(const bf16x8*)(base + swz64(row * 64 + lg * 16));
}

__device__ __forceinline__ void read_af(const char* Ac, int wm, int mh,
                                        int l15, int lg, bf16x8 (&af)[4]) {
#pragma unroll
  for (int m = 0; m < 4; ++m)
    af[m] = ldsw_read(Ac, wm * 128 + (mh * 4 + m) * 16 + l15, lg);
}
__device__ __forceinline__ void read_bf(const char* Bc, int wn,
                                        int l15, int lg, bf16x8 (&bf)[4]) {
#pragma unroll
  for (int n = 0; n < 4; ++n)
    bf[n] = ldsw_read(Bc, wn * 64 + n * 16 + l15, lg);
}

#define MFMA16(BASE)                                                          \
  do {                                                                        \
    MIDBAR();                                                                 \
    __builtin_amdgcn_s_setprio(1);                                            \
    _Pragma("unroll")                                                         \
    for (int m = 0; m < 4; ++m)                                               \
      _Pragma("unroll")                                                       \
      for (int n = 0; n < 4; ++n)                                             \
        acc[(BASE) + m][n] = __builtin_amdgcn_mfma_f32_16x16x32_bf16(         \
            af[m], bf[n], acc[(BASE) + m][n], 0, 0, 0);                       \
    __builtin_amdgcn_s_setprio(0);                                            \
  } while (0)

// ---- Core C (round-13/14): BK=32, 64KB LDS -> 2 blocks/CU. Per kt: 2 phases.
// buf(kt) = smem + (kt&1)*32768; A @+0, B @+16384. Stage kt+1 into the other
// buffer (its reads completed at kt-1's lgkm0 barrier); vmcnt(0) at kt end
// guarantees kt+1's chunks landed before kt+1 reads. TLP (2 blocks/CU) hides
// the drains. LINB: B operand is blocked-linear (8192-elem chunk stride). ----
template <bool LINB>
__device__ __forceinline__ void gemm_core_C(
    const ushort* __restrict__ Ab, const ushort* __restrict__ Bb,
    int lda, int NT, char* smem, f32x4 (&acc)[8][4],
    int tid, int wm, int wn, int l15, int lg)
{
  stage_chunk(Ab, lda, smem + 0, tid);
  if (LINB) stage_lin(Bb, smem + 16384, tid);
  else      stage_chunk(Bb, lda, smem + 16384, tid);
  ENDBARV0();

#pragma unroll 1
  for (int kt = 0; kt < NT; ++kt) {
    char* cb = smem + (kt & 1) * 32768;
    char* nb = smem + (((kt & 1) ^ 1) * 32768);
    const bool pf = (kt + 1 < NT);
    const ushort* An = Ab + (size_t)(kt + 1) * 32;
    const ushort* Bn = LINB ? (Bb + (size_t)(kt + 1) * 8192)
                            : (Bb + (size_t)(kt + 1) * 32);
    bf16x8 af[4], bf[4];

    // ph-A
    read_af(cb + 0, wm, 0, l15, lg, af);
    read_bf(cb + 16384, wn, l15, lg, bf);
    if (pf) stage_chunk(An, lda, nb + 0, tid);
    MFMA16(0);
    ENDBAR();

    // ph-B
    read_af(cb + 0, wm, 1, l15, lg, af);
    if (pf) {
      if (LINB) stage_lin(Bn, nb + 16384, tid);
      else      stage_chunk(Bn, lda, nb + 16384, tid);
    }
    MFMA16(4);
    ENDBARV0();
  }
}

// GEMM1: S = exp2(Q'.K^T) (log2e/32 folded into Q), BLOCKED S layout:
// [batch][by][bx][8 x 16KB chunk image] (chunk = 32-t slab). Continuous
// 128-kt pipeline per block (4 t-groups x 32 k-slabs = full K=1024 per
// group — round-13 bug was 16 slabs = half of K). Group epilogue =
// register-direct plain 8B stores after the group's final vmcnt(0) barrier.
__global__ __launch_bounds__(512, 4) void gemm1_256(
    const ushort* __restrict__ Q, const ushort* __restrict__ K,
    ushort* __restrict__ S, float* __restrict__ Rsum,
    int b0, size_t s_stride)
{
  extern __shared__ char smem[];
  const int tid  = threadIdx.x;
  const int lane = tid & 63;
  const int wave = tid >> 6;
  const int wm = wave >> 2, wn = wave & 3;
  const int l15 = lane & 15, lg = lane >> 4;

  int by, bxx, bzc;
  if (gridDim.x == 8 * 64) {
    const int hw = blockIdx.x;
    bzc = hw & 7;                  // batch -> XCD
    const int inner = hw >> 3;     // 0..63
    bxx = inner & 3;               // fastest: t-quarter
    by  = inner >> 2;              // 0..15
  } else {
    by = blockIdx.y; bxx = blockIdx.x; bzc = 0;
  }

  const int bz   = b0 + bzc;
  const int row0 = by * 256;                       // v rows
  const ushort* Qb  = Q + (size_t)bz * NSEQ * DIMD + (size_t)row0 * DIMD;
  const ushort* Kb0 = K + (size_t)bz * NSEQ * DIMD
                    + (size_t)(bxx * 4) * 256 * DIMD;  // group-0 K panel
  char* Sreg = (char*)(S + (size_t)bzc * s_stride + (size_t)by * 1048576)
             + (size_t)bxx * 4 * 131072;

  f32x4 acc[8][4];
#pragma unroll
  for (int m = 0; m < 8; ++m)
#pragma unroll
    for (int n = 0; n < 4; ++n) acc[m][n] = 0.0f;
  float vsum[4] = {0.f, 0.f, 0.f, 0.f};

  // prologue: kt=0 chunks (K-panel g0 k-slab 0, Q k-slab 0)
  stage_chunk(Kb0, DIMD, smem + 0,     tid);
  stage_chunk(Qb,  DIMD, smem + 16384, tid);
  ENDBARV0();

#pragma unroll 1
  for (int kt = 0; kt < 128; ++kt) {
    char* cb = smem + (kt & 1) * 32768;
    char* nb = smem + (((kt & 1) ^ 1) * 32768);
    const int vn = kt + 1;
    const bool pf = (vn < 128);
    // next chunk: group g = vn>>5 selects K panel, k-slab = vn&31 (x32 elems)
    const ushort* An = Kb0 + (size_t)(vn >> 5) * 256 * DIMD + (vn & 31) * 32;
    const ushort* Bn = Qb + (vn & 31) * 32;
    bf16x8 af[4], bf[4];

    // ph-A
    read_af(cb + 0, wm, 0, l15, lg, af);
    read_bf(cb + 16384, wn, l15, lg, bf);
    if (pf) stage_chunk(An, DIMD, nb + 0, tid);
    MFMA16(0);
    ENDBAR();

    // ph-B
    read_af(cb + 0, wm, 1, l15, lg, af);
    if (pf) stage_chunk(Bn, DIMD, nb + 16384, tid);
    MFMA16(4);
    ENDBARV0();

    if ((kt & 31) == 31) {
      // ---- group epilogue: p = exp2(s'), plain 8B stores to blocked S ----
      char* region = Sreg + (size_t)(kt >> 5) * 131072;
#pragma unroll
      for (int ti = 0; ti < 8; ++ti) {
        const int tl   = wm * 128 + ti * 16 + lg * 4;
        const int ktl  = tl >> 6;
        const int half = (tl >> 5) & 1;
        const int tcol = tl & 31;
        char* img = region + (ktl * 2 + half) * 16384;
#pragma unroll
        for (int vi = 0; vi < 4; ++vi) {
          const int vrow = wn * 64 + vi * 16 + l15;
          float p0 = fexp2(acc[ti][vi][0]);
          float p1 = fexp2(acc[ti][vi][1]);
          float p2 = fexp2(acc[ti][vi][2]);
          float p3 = fexp2(acc[ti][vi][3]);
          vsum[vi] += (p0 + p1) + (p2 + p3);
          unsigned long long pk =
              (unsigned long long)f2bf(p0)        |
              ((unsigned long long)f2bf(p1) << 16) |
              ((unsigned long long)f2bf(p2) << 32) |
              ((unsigned long long)f2bf(p3) << 48);
          *(unsigned long long*)(img + swz64(vrow * 64 + tcol * 2)) = pk;
        }
      }
#pragma unroll
      for (int m = 0; m < 8; ++m)
#pragma unroll
        for (int n = 0; n < 4; ++n) acc[m][n] = 0.0f;
    }
  }

  float* Rs = Rsum + (size_t)bz * NSEQ;
#pragma unroll
  for (int vi = 0; vi < 4; ++vi) {
    float s = vsum[vi];
    s += __shfl_xor(s, 16, 64);
    s += __shfl_xor(s, 32, 64);
    if (lg == 0)
      atomicAdd(Rs + row0 + wn * 64 + vi * 16 + l15, s);
  }
}

// GEMM2: O = (S.V)/Rsum stored [v][d]. A-role = Vt (swizzle-staged, NT=128);
// B-role = S in blocked layout (one 16KB chunk per kt, linear stage).
__global__ __launch_bounds__(512, 4) void gemm2_256(
    const ushort* __restrict__ S, const ushort* __restrict__ Kt,
    const float* __restrict__ Rsum, float* __restrict__ Out,
    int b0, size_t s_stride)
{
  extern __shared__ char smem[];
  const int tid  = threadIdx.x;
  const int lane = tid & 63;
  const int wave = tid >> 6;
  const int wm = wave >> 2, wn = wave & 3;
  const int l15 = lane & 15, lg = lane >> 4;

  int bx, by, bzc;
  if (gridDim.z == BATCH) {
    const int hw = blockIdx.x + (blockIdx.y << 2) + (blockIdx.z << 6);
    bzc = hw & 7;
    const int inner = hw >> 3;
    bx = inner & 3; by = inner >> 2;
  } else {
    bx = blockIdx.x; by = blockIdx.y; bzc = 0;
  }

  const int bz   = b0 + bzc;
  const int row0 = by * 256;   // v rows
  const int col0 = bx * 256;   // d cols
  const ushort* Sbase = S + (size_t)bzc * s_stride + (size_t)by * 1048576;
  const ushort* Vtb = Kt + ((size_t)bz * DIMD + col0) * NSEQ;

  f32x4 acc[8][4];
#pragma unroll
  for (int m = 0; m < 8; ++m)
#pragma unroll
    for (int n = 0; n < 4; ++n) acc[m][n] = 0.0f;

  // swapped: A-role (C rows = d) = Vt; B-role (C cols = v) = blocked S
  gemm_core_C<true>(Vtb, Sbase, NSEQ, NSEQ / 32, smem, acc,
                    tid, wm, wn, l15, lg);

  const float* Rs = Rsum + (size_t)bz * NSEQ;
  float* Ob = Out + (size_t)bz * NSEQ * DIMD;
  float inv[4];
#pragma unroll
  for (int vi = 0; vi < 4; ++vi)
    inv[vi] = 1.0f / Rs[row0 + wn * 64 + vi * 16 + l15];
#pragma unroll
  for (int di = 0; di < 8; ++di) {
#pragma unroll
    for (int vi = 0; vi < 4; ++vi) {
      const int v = row0 + wn * 64 + vi * 16 + l15;
      const int d = col0 + wm * 128 + di * 16 + lg * 4;
      f32x4 o = acc[di][vi] * inv[vi];
      *(f32x4*)(Ob + (size_t)v * DIMD + d) = o;
    }
  }
}

extern "C" void kernel_launch(void* const* d_in, const int* in_sizes, int n_in,
                              void* d_out, int out_size, void* d_ws, size_t ws_size,
                              hipStream_t stream) {
  const float* vis = (const float*)d_in[0];
  const float* txt = (const float*)d_in[1];
  const float* gv  = (const float*)d_in[2];
  const float* bv  = (const float*)d_in[3];
  const float* gt  = (const float*)d_in[4];
  const float* bt  = (const float*)d_in[5];
  float* out = (float*)d_out;

  const size_t tokens = (size_t)BATCH * NSEQ * DIMD;      // 33,554,432 elems
  ushort* Qbf = (ushort*)d_ws;                            // 64 MiB
  ushort* Kbf = Qbf + tokens;                             // 64 MiB
  ushort* Ktb = Kbf + tokens;                             // 64 MiB
  char*   wsb = (char*)d_ws;
  float*  Rsum = (float*)(wsb + 201326592);               // @192 MiB
  ushort* Sbuf = (ushort*)(wsb + 201457664);              // S region (blocked)

  const size_t S_FULL = (size_t)BATCH * NSEQ * NSEQ * 2;  // 256 MiB
  const size_t NEED_FULL = 201457664 + S_FULL;

  // Q scale = (1/sqrt(1024)) * log2(e), so scores are in exp2 domain
  ln_bf16_kernel<<<BATCH * NSEQ / 4, 256, 0, stream>>>(vis, gv, bv, Qbf,
                                                       0.045084219f);
  ln_bf16_kernel<<<BATCH * NSEQ / 4, 256, 0, stream>>>(txt, gt, bt, Kbf, 1.0f);
  transpose_kernel<<<BATCH * (NSEQ / 64) * (DIMD / 64), 256, 0, stream>>>(Kbf, Ktb);

  (void)hipFuncSetAttribute((const void*)gemm1_256,
                      hipFuncAttributeMaxDynamicSharedMemorySize, 65536);
  (void)hipFuncSetAttribute((const void*)gemm2_256,
                      hipFuncAttributeMaxDynamicSharedMemorySize, 65536);

  (void)hipMemsetAsync(Rsum, 0, (size_t)BATCH * NSEQ * sizeof(float), stream);

  if (ws_size >= NEED_FULL) {
    gemm1_256<<<dim3(8 * 64, 1, 1), 512, 65536, stream>>>(
        Qbf, Kbf, Sbuf, Rsum, 0, (size_t)NSEQ * NSEQ);
    gemm2_256<<<dim3(4, 16, BATCH), 512, 65536, stream>>>(
        Sbuf, Ktb, Rsum, out, 0, (size_t)NSEQ * NSEQ);
  } else {
    for (int b = 0; b < BATCH; ++b) {
      gemm1_256<<<dim3(4, 16, 1), 512, 65536, stream>>>(
          Qbf, Kbf, Sbuf, Rsum, b, 0);
      gemm2_256<<<dim3(4, 16, 1), 512, 65536, stream>>>(
          Sbuf, Ktb, Rsum, out, b, 0);
    }
  }
}

// Round 15
// 750.632 us; speedup vs baseline: 7.5188x; 7.5188x over previous
//
#include <hip/hip_runtime.h>
#include <hip/hip_bf16.h>
#include <stdint.h>

#define DIMD 1024
#define NSEQ 4096
#define BATCH 8
#define LN_EPS 1e-5f

typedef __attribute__((ext_vector_type(8))) short bf16x8;
typedef __attribute__((ext_vector_type(4))) float f32x4;

__device__ __forceinline__ ushort f2bf(float f) {
  union { __hip_bfloat16 h; ushort u; } cv;
  cv.h = __float2bfloat16(f);
  return cv.u;
}

__device__ __forceinline__ float fexp2(float x) {
  return exp2f(x);   // maps to v_exp_f32
}

__device__ __forceinline__ void gload16(const void* g, void* l) {
  __builtin_amdgcn_global_load_lds(
      (const __attribute__((address_space(1))) uint32_t*)g,
      (__attribute__((address_space(3))) uint32_t*)l, 16, 0, 0);
}

#define MIDBAR()   asm volatile("s_barrier" ::: "memory")
#define ENDBAR()   asm volatile("s_waitcnt lgkmcnt(0)\n\ts_barrier" ::: "memory")
#define ENDBARV0() asm volatile("s_waitcnt vmcnt(0) lgkmcnt(0)\n\ts_barrier" ::: "memory")

// LDS XOR swizzle (involution). Verified round 5: SQ_LDS_BANK_CONFLICT == 0.
__device__ __forceinline__ int swz64(int byte) {
  return byte ^ (((byte >> 7) & 3) << 4);
}

// ---------------- LayerNorm (fp32 in -> bf16 out, scale folded) -------------
__global__ __launch_bounds__(256) void ln_bf16_kernel(
    const float* __restrict__ x, const float* __restrict__ gamma,
    const float* __restrict__ beta, ushort* __restrict__ y, float scale)
{
  const int lane = threadIdx.x & 63;
  const int wv   = threadIdx.x >> 6;
  const size_t row = (size_t)blockIdx.x * 4 + wv;
  const float* xr = x + row * DIMD;

  float4 v[4];
#pragma unroll
  for (int c = 0; c < 4; ++c)
    v[c] = *(const float4*)(xr + c * 256 + lane * 4);

  float s = 0.f;
#pragma unroll
  for (int c = 0; c < 4; ++c) s += v[c].x + v[c].y + v[c].z + v[c].w;
#pragma unroll
  for (int m = 32; m >= 1; m >>= 1) s += __shfl_xor(s, m, 64);
  const float mean = s * (1.0f / DIMD);

  float vs = 0.f;
#pragma unroll
  for (int c = 0; c < 4; ++c) {
    float a0 = v[c].x - mean, a1 = v[c].y - mean;
    float a2 = v[c].z - mean, a3 = v[c].w - mean;
    vs += a0 * a0 + a1 * a1 + a2 * a2 + a3 * a3;
  }
#pragma unroll
  for (int m = 32; m >= 1; m >>= 1) vs += __shfl_xor(vs, m, 64);
  const float rstd = rsqrtf(vs * (1.0f / DIMD) + LN_EPS);

  ushort* yr = y + row * DIMD;
#pragma unroll
  for (int c = 0; c < 4; ++c) {
    const int d = c * 256 + lane * 4;
    float4 g  = *(const float4*)(gamma + d);
    float4 bb = *(const float4*)(beta + d);
    ushort4 o;
    o.x = f2bf(((v[c].x - mean) * rstd * g.x + bb.x) * scale);
    o.y = f2bf(((v[c].y - mean) * rstd * g.y + bb.y) * scale);
    o.z = f2bf(((v[c].z - mean) * rstd * g.z + bb.z) * scale);
    o.w = f2bf(((v[c].w - mean) * rstd * g.w + bb.w) * scale);
    *(ushort4*)(yr + d) = o;
  }
}

// ---------------- bf16 transpose: [b][n][d] -> [b][d][n] --------------------
__global__ __launch_bounds__(256) void transpose_kernel(
    const ushort* __restrict__ src, ushort* __restrict__ dst)
{
  __shared__ ushort tile[64][72];
  const int t   = threadIdx.x;
  const int bid = blockIdx.x;
  const int b   = bid >> 10;
  const int rem = bid & 1023;
  const int n0  = (rem >> 4) << 6;
  const int d0  = (rem & 15) << 6;
  const ushort* sb = src + ((size_t)b * NSEQ) * DIMD;
  ushort* db       = dst + ((size_t)b * DIMD) * NSEQ;

#pragma unroll
  for (int k = 0; k < 2; ++k) {
    int c = t + 256 * k;
    int r = c >> 3, scol = (c & 7) * 8;
    *(uint4*)&tile[r][scol] =
        *(const uint4*)(sb + (size_t)(n0 + r) * DIMD + d0 + scol);
  }
  __syncthreads();
#pragma unroll
  for (int k = 0; k < 2; ++k) {
    int c = t + 256 * k;
    int dr = c >> 3, ns = (c & 7) * 8;
    union { ushort u[8]; uint4 q; } tv;
#pragma unroll
    for (int i = 0; i < 8; ++i) tv.u[i] = tile[ns + i][dr];
    *(uint4*)(db + (size_t)(d0 + dr) * NSEQ + n0 + ns) = tv.q;
  }
}

// ================== shared GEMM building blocks =============================
// chunk = [256 rows][32 k-cols] bf16 = 16KB, swz64-swizzled image.
__device__ __forceinline__ void stage_chunk(const ushort* __restrict__ g,
                                            int ld, char* l, int tid) {
  const int o0 = tid * 16;
  const int o1 = o0 + 8192;
  const int s0 = swz64(o0);
  const int s1 = swz64(o1);
  gload16(g + (size_t)(s0 >> 6) * ld + ((s0 & 63) >> 1), l + o0);
  gload16(g + (size_t)(s1 >> 6) * ld + ((s1 & 63) >> 1), l + o1);
}

// linear stage: global already holds the swizzled 16KB chunk image
__device__ __forceinline__ void stage_lin(const ushort* __restrict__ g,
                                          char* l, int tid) {
  gload16(g + tid * 8,        l + tid * 16);
  gload16(g + 4096 + tid * 8, l + tid * 16 + 8192);
}

__device__ __forceinline__ bf16x8 ldsw_read(const char* base, int row, int lg) {
  return *(const bf16x8*)(base + swz64(row * 64 + lg * 16));
}

__device__ __forceinline__ void read_af(const char* Ac, int wm, int mh,
                                        int l15, int lg, bf16x8 (&af)[4]) {
#pragma unroll
  for (int m = 0; m < 4; ++m)
    af[m] = ldsw_read(Ac, wm * 128 + (mh * 4 + m) * 16 + l15, lg);
}
__device__ __forceinline__ void read_bf(const char* Bc, int wn,
                                        int l15, int lg, bf16x8 (&bf)[4]) {
#pragma unroll
  for (int n = 0; n < 4; ++n)
    bf[n] = ldsw_read(Bc, wn * 64 + n * 16 + l15, lg);
}

#define MFMA16(BASE)                                                          \
  do {                                                                        \
    MIDBAR();                                                                 \
    __builtin_amdgcn_s_setprio(1);                                            \
    _Pragma("unroll")                                                         \
    for (int m = 0; m < 4; ++m)                                               \
      _Pragma("unroll")                                                       \
      for (int n = 0; n < 4; ++n)                                             \
        acc[(BASE) + m][n] = __builtin_amdgcn_mfma_f32_16x16x32_bf16(         \
            af[m], bf[n], acc[(BASE) + m][n], 0, 0, 0);                       \
    __builtin_amdgcn_s_setprio(0);                                            \
  } while (0)

// ---- Core C: BK=32, 64KB LDS. Per kt: 2 phases. buf(kt) = smem +
// (kt&1)*32768; A @+0, B @+16384. Stage kt+1 into the other buffer (its
// reads completed at kt-1's lgkm0 barrier); vmcnt(0) at kt end guarantees
// kt+1's chunks landed before kt+1 reads. 2 blocks/CU TLP hides the drains.
// LINB: B operand is blocked-linear (8192-elem chunk stride). ----------------
template <bool LINB>
__device__ __forceinline__ void gemm_core_C(
    const ushort* __restrict__ Ab, const ushort* __restrict__ Bb,
    int lda, int NT, char* smem, f32x4 (&acc)[8][4],
    int tid, int wm, int wn, int l15, int lg)
{
  stage_chunk(Ab, lda, smem + 0, tid);
  if (LINB) stage_lin(Bb, smem + 16384, tid);
  else      stage_chunk(Bb, lda, smem + 16384, tid);
  ENDBARV0();

#pragma unroll 1
  for (int kt = 0; kt < NT; ++kt) {
    char* cb = smem + (kt & 1) * 32768;
    char* nb = smem + (((kt & 1) ^ 1) * 32768);
    const bool pf = (kt + 1 < NT);
    const ushort* An = Ab + (size_t)(kt + 1) * 32;
    const ushort* Bn = LINB ? (Bb + (size_t)(kt + 1) * 8192)
                            : (Bb + (size_t)(kt + 1) * 32);
    bf16x8 af[4], bf[4];

    // ph-A
    read_af(cb + 0, wm, 0, l15, lg, af);
    read_bf(cb + 16384, wn, l15, lg, bf);
    if (pf) stage_chunk(An, lda, nb + 0, tid);
    MFMA16(0);
    ENDBAR();

    // ph-B
    read_af(cb + 0, wm, 1, l15, lg, af);
    if (pf) {
      if (LINB) stage_lin(Bn, nb + 16384, tid);
      else      stage_chunk(Bn, lda, nb + 16384, tid);
    }
    MFMA16(4);
    ENDBARV0();
  }
}

// GEMM1: S = exp2(Q'.K^T) (log2e/32 folded into Q), BLOCKED S layout:
// [batch][by][bx][8 x 16KB chunk image] (chunk = 32-t slab). Continuous
// 128-kt pipeline per block (4 t-groups x 32 k-slabs = full K=1024/group).
// Group epilogue = register-direct plain 8B stores after the group's final
// vmcnt(0) barrier. launch_bounds (512,2): VGPR cap 256 (allocator ~116-128
// -> 2 blocks/CU fit with 64KB LDS). Round-14's (512,4) forced 64 VGPR ->
// accumulator spill -> 16GB scratch traffic.
__global__ __launch_bounds__(512, 2) void gemm1_256(
    const ushort* __restrict__ Q, const ushort* __restrict__ K,
    ushort* __restrict__ S, float* __restrict__ Rsum,
    int b0, size_t s_stride)
{
  extern __shared__ char smem[];
  const int tid  = threadIdx.x;
  const int lane = tid & 63;
  const int wave = tid >> 6;
  const int wm = wave >> 2, wn = wave & 3;
  const int l15 = lane & 15, lg = lane >> 4;

  int by, bxx, bzc;
  if (gridDim.x == 8 * 64) {
    const int hw = blockIdx.x;
    bzc = hw & 7;                  // batch -> XCD
    const int inner = hw >> 3;     // 0..63
    bxx = inner & 3;               // fastest: t-quarter
    by  = inner >> 2;              // 0..15
  } else {
    by = blockIdx.y; bxx = blockIdx.x; bzc = 0;
  }

  const int bz   = b0 + bzc;
  const int row0 = by * 256;                       // v rows
  const ushort* Qb  = Q + (size_t)bz * NSEQ * DIMD + (size_t)row0 * DIMD;
  const ushort* Kb0 = K + (size_t)bz * NSEQ * DIMD
                    + (size_t)(bxx * 4) * 256 * DIMD;  // group-0 K panel
  char* Sreg = (char*)(S + (size_t)bzc * s_stride + (size_t)by * 1048576)
             + (size_t)bxx * 4 * 131072;

  f32x4 acc[8][4];
#pragma unroll
  for (int m = 0; m < 8; ++m)
#pragma unroll
    for (int n = 0; n < 4; ++n) acc[m][n] = 0.0f;
  float vsum[4] = {0.f, 0.f, 0.f, 0.f};

  // prologue: kt=0 chunks (K-panel g0 k-slab 0, Q k-slab 0)
  stage_chunk(Kb0, DIMD, smem + 0,     tid);
  stage_chunk(Qb,  DIMD, smem + 16384, tid);
  ENDBARV0();

#pragma unroll 1
  for (int kt = 0; kt < 128; ++kt) {
    char* cb = smem + (kt & 1) * 32768;
    char* nb = smem + (((kt & 1) ^ 1) * 32768);
    const int vn = kt + 1;
    const bool pf = (vn < 128);
    // next chunk: group g = vn>>5 selects K panel, k-slab = vn&31 (x32 elems)
    const ushort* An = Kb0 + (size_t)(vn >> 5) * 256 * DIMD + (vn & 31) * 32;
    const ushort* Bn = Qb + (vn & 31) * 32;
    bf16x8 af[4], bf[4];

    // ph-A
    read_af(cb + 0, wm, 0, l15, lg, af);
    read_bf(cb + 16384, wn, l15, lg, bf);
    if (pf) stage_chunk(An, DIMD, nb + 0, tid);
    MFMA16(0);
    ENDBAR();

    // ph-B
    read_af(cb + 0, wm, 1, l15, lg, af);
    if (pf) stage_chunk(Bn, DIMD, nb + 16384, tid);
    MFMA16(4);
    ENDBARV0();

    if ((kt & 31) == 31) {
      // ---- group epilogue: p = exp2(s'), plain 8B stores to blocked S ----
      char* region = Sreg + (size_t)(kt >> 5) * 131072;
#pragma unroll
      for (int ti = 0; ti < 8; ++ti) {
        const int tl   = wm * 128 + ti * 16 + lg * 4;
        const int ktl  = tl >> 6;
        const int half = (tl >> 5) & 1;
        const int tcol = tl & 31;
        char* img = region + (ktl * 2 + half) * 16384;
#pragma unroll
        for (int vi = 0; vi < 4; ++vi) {
          const int vrow = wn * 64 + vi * 16 + l15;
          float p0 = fexp2(acc[ti][vi][0]);
          float p1 = fexp2(acc[ti][vi][1]);
          float p2 = fexp2(acc[ti][vi][2]);
          float p3 = fexp2(acc[ti][vi][3]);
          vsum[vi] += (p0 + p1) + (p2 + p3);
          unsigned long long pk =
              (unsigned long long)f2bf(p0)        |
              ((unsigned long long)f2bf(p1) << 16) |
              ((unsigned long long)f2bf(p2) << 32) |
              ((unsigned long long)f2bf(p3) << 48);
          *(unsigned long long*)(img + swz64(vrow * 64 + tcol * 2)) = pk;
        }
      }
#pragma unroll
      for (int m = 0; m < 8; ++m)
#pragma unroll
        for (int n = 0; n < 4; ++n) acc[m][n] = 0.0f;
    }
  }

  float* Rs = Rsum + (size_t)bz * NSEQ;
#pragma unroll
  for (int vi = 0; vi < 4; ++vi) {
    float s = vsum[vi];
    s += __shfl_xor(s, 16, 64);
    s += __shfl_xor(s, 32, 64);
    if (lg == 0)
      atomicAdd(Rs + row0 + wn * 64 + vi * 16 + l15, s);
  }
}

// GEMM2: O = (S.V)/Rsum stored [v][d]. A-role = Vt (swizzle-staged, NT=128);
// B-role = S in blocked layout (one 16KB chunk per kt, linear stage).
__global__ __launch_bounds__(512, 2) void gemm2_256(
    const ushort* __restrict__ S, const ushort* __restrict__ Kt,
    const float* __restrict__ Rsum, float* __restrict__ Out,
    int b0, size_t s_stride)
{
  extern __shared__ char smem[];
  const int tid  = threadIdx.x;
  const int lane = tid & 63;
  const int wave = tid >> 6;
  const int wm = wave >> 2, wn = wave & 3;
  const int l15 = lane & 15, lg = lane >> 4;

  int bx, by, bzc;
  if (gridDim.z == BATCH) {
    const int hw = blockIdx.x + (blockIdx.y << 2) + (blockIdx.z << 6);
    bzc = hw & 7;
    const int inner = hw >> 3;
    bx = inner & 3; by = inner >> 2;
  } else {
    bx = blockIdx.x; by = blockIdx.y; bzc = 0;
  }

  const int bz   = b0 + bzc;
  const int row0 = by * 256;   // v rows
  const int col0 = bx * 256;   // d cols
  const ushort* Sbase = S + (size_t)bzc * s_stride + (size_t)by * 1048576;
  const ushort* Vtb = Kt + ((size_t)bz * DIMD + col0) * NSEQ;

  f32x4 acc[8][4];
#pragma unroll
  for (int m = 0; m < 8; ++m)
#pragma unroll
    for (int n = 0; n < 4; ++n) acc[m][n] = 0.0f;

  // swapped: A-role (C rows = d) = Vt; B-role (C cols = v) = blocked S
  gemm_core_C<true>(Vtb, Sbase, NSEQ, NSEQ / 32, smem, acc,
                    tid, wm, wn, l15, lg);

  const float* Rs = Rsum + (size_t)bz * NSEQ;
  float* Ob = Out + (size_t)bz * NSEQ * DIMD;
  float inv[4];
#pragma unroll
  for (int vi = 0; vi < 4; ++vi)
    inv[vi] = 1.0f / Rs[row0 + wn * 64 + vi * 16 + l15];
#pragma unroll
  for (int di = 0; di < 8; ++di) {
#pragma unroll
    for (int vi = 0; vi < 4; ++vi) {
      const int v = row0 + wn * 64 + vi * 16 + l15;
      const int d = col0 + wm * 128 + di * 16 + lg * 4;
      f32x4 o = acc[di][vi] * inv[vi];
      *(f32x4*)(Ob + (size_t)v * DIMD + d) = o;
    }
  }
}

extern "C" void kernel_launch(void* const* d_in, const int* in_sizes, int n_in,
                              void* d_out, int out_size, void* d_ws, size_t ws_size,
                              hipStream_t stream) {
  const float* vis = (const float*)d_in[0];
  const float* txt = (const float*)d_in[1];
  const float* gv  = (const float*)d_in[2];
  const float* bv  = (const float*)d_in[3];
  const float* gt  = (const float*)d_in[4];
  const float* bt  = (const float*)d_in[5];
  float* out = (float*)d_out;

  const size_t tokens = (size_t)BATCH * NSEQ * DIMD;      // 33,554,432 elems
  ushort* Qbf = (ushort*)d_ws;                            // 64 MiB
  ushort* Kbf = Qbf + tokens;                             // 64 MiB
  ushort* Ktb = Kbf + tokens;                             // 64 MiB
  char*   wsb = (char*)d_ws;
  float*  Rsum = (float*)(wsb + 201326592);               // @192 MiB
  ushort* Sbuf = (ushort*)(wsb + 201457664);              // S region (blocked)

  const size_t S_FULL = (size_t)BATCH * NSEQ * NSEQ * 2;  // 256 MiB
  const size_t NEED_FULL = 201457664 + S_FULL;

  // Q scale = (1/sqrt(1024)) * log2(e), so scores are in exp2 domain
  ln_bf16_kernel<<<BATCH * NSEQ / 4, 256, 0, stream>>>(vis, gv, bv, Qbf,
                                                       0.045084219f);
  ln_bf16_kernel<<<BATCH * NSEQ / 4, 256, 0, stream>>>(txt, gt, bt, Kbf, 1.0f);
  transpose_kernel<<<BATCH * (NSEQ / 64) * (DIMD / 64), 256, 0, stream>>>(Kbf, Ktb);

  (void)hipFuncSetAttribute((const void*)gemm1_256,
                      hipFuncAttributeMaxDynamicSharedMemorySize, 65536);
  (void)hipFuncSetAttribute((const void*)gemm2_256,
                      hipFuncAttributeMaxDynamicSharedMemorySize, 65536);

  (void)hipMemsetAsync(Rsum, 0, (size_t)BATCH * NSEQ * sizeof(float), stream);

  if (ws_size >= NEED_FULL) {
    gemm1_256<<<dim3(8 * 64, 1, 1), 512, 65536, stream>>>(
        Qbf, Kbf, Sbuf, Rsum, 0, (size_t)NSEQ * NSEQ);
    gemm2_256<<<dim3(4, 16, BATCH), 512, 65536, stream>>>(
        Sbuf, Ktb, Rsum, out, 0, (size_t)NSEQ * NSEQ);
  } else {
    for (int b = 0; b < BATCH; ++b) {
      gemm1_256<<<dim3(4, 16, 1), 512, 65536, stream>>>(
          Qbf, Kbf, Sbuf, Rsum, b, 0);
      gemm2_256<<<dim3(4, 16, 1), 512, 65536, stream>>>(
          Sbuf, Ktb, Rsum, out, b, 0);
    }
  }
}

// Round 16
// 609.667 us; speedup vs baseline: 9.2573x; 1.2312x over previous
//
#include <hip/hip_runtime.h>
#include <hip/hip_bf16.h>
#include <stdint.h>

#define DIMD 1024
#define NSEQ 4096
#define BATCH 8
#define LN_EPS 1e-5f

typedef __attribute__((ext_vector_type(8))) short bf16x8;
typedef __attribute__((ext_vector_type(4))) float f32x4;
typedef __attribute__((ext_vector_type(4))) unsigned int u32x4;

__device__ __forceinline__ ushort f2bf(float f) {
  union { __hip_bfloat16 h; ushort u; } cv;
  cv.h = __float2bfloat16(f);
  return cv.u;
}

__device__ __forceinline__ float fexp2(float x) {
  return exp2f(x);   // maps to v_exp_f32
}

__device__ __forceinline__ void gload16(const void* g, void* l) {
  __builtin_amdgcn_global_load_lds(
      (const __attribute__((address_space(1))) uint32_t*)g,
      (__attribute__((address_space(3))) uint32_t*)l, 16, 0, 0);
}

#define MIDBAR()   asm volatile("s_barrier" ::: "memory")
#define ENDBAR()   asm volatile("s_waitcnt lgkmcnt(0)\n\ts_barrier" ::: "memory")
#define ENDBARV4() asm volatile("s_waitcnt vmcnt(4) lgkmcnt(0)\n\ts_barrier" ::: "memory")
#define ENDBARV0() asm volatile("s_waitcnt vmcnt(0) lgkmcnt(0)\n\ts_barrier" ::: "memory")

// LDS XOR swizzle (involution). Verified round 5: SQ_LDS_BANK_CONFLICT == 0.
__device__ __forceinline__ int swz64(int byte) {
  return byte ^ (((byte >> 7) & 3) << 4);
}

// ------------- Fused dual LayerNorm (visual+text in one dispatch) -----------
__global__ __launch_bounds__(256) void ln2_bf16_kernel(
    const float* __restrict__ vis, const float* __restrict__ gv,
    const float* __restrict__ bv, ushort* __restrict__ Qbf,
    const float* __restrict__ txt, const float* __restrict__ gt,
    const float* __restrict__ bt, ushort* __restrict__ Kbf)
{
  const int bid  = blockIdx.x;
  const int half = BATCH * NSEQ / 4;          // 8192 blocks per tensor
  const float* x; const float* gamma; const float* beta;
  ushort* y; float scale; size_t row0;
  if (bid < half) {
    x = vis; gamma = gv; beta = bv; y = Qbf;
    scale = 0.045084219f;                     // (1/32) * log2(e)
    row0 = (size_t)bid * 4;
  } else {
    x = txt; gamma = gt; beta = bt; y = Kbf;
    scale = 1.0f;
    row0 = (size_t)(bid - half) * 4;
  }

  const int lane = threadIdx.x & 63;
  const int wv   = threadIdx.x >> 6;
  const size_t row = row0 + wv;
  const float* xr = x + row * DIMD;

  float4 v[4];
#pragma unroll
  for (int c = 0; c < 4; ++c)
    v[c] = *(const float4*)(xr + c * 256 + lane * 4);

  float s = 0.f;
#pragma unroll
  for (int c = 0; c < 4; ++c) s += v[c].x + v[c].y + v[c].z + v[c].w;
#pragma unroll
  for (int m = 32; m >= 1; m >>= 1) s += __shfl_xor(s, m, 64);
  const float mean = s * (1.0f / DIMD);

  float vs = 0.f;
#pragma unroll
  for (int c = 0; c < 4; ++c) {
    float a0 = v[c].x - mean, a1 = v[c].y - mean;
    float a2 = v[c].z - mean, a3 = v[c].w - mean;
    vs += a0 * a0 + a1 * a1 + a2 * a2 + a3 * a3;
  }
#pragma unroll
  for (int m = 32; m >= 1; m >>= 1) vs += __shfl_xor(vs, m, 64);
  const float rstd = rsqrtf(vs * (1.0f / DIMD) + LN_EPS);

  ushort* yr = y + row * DIMD;
#pragma unroll
  for (int c = 0; c < 4; ++c) {
    const int d = c * 256 + lane * 4;
    float4 g  = *(const float4*)(gamma + d);
    float4 bb = *(const float4*)(beta + d);
    ushort4 o;
    o.x = f2bf(((v[c].x - mean) * rstd * g.x + bb.x) * scale);
    o.y = f2bf(((v[c].y - mean) * rstd * g.y + bb.y) * scale);
    o.z = f2bf(((v[c].z - mean) * rstd * g.z + bb.z) * scale);
    o.w = f2bf(((v[c].w - mean) * rstd * g.w + bb.w) * scale);
    *(ushort4*)(yr + d) = o;
  }
}

// ---------------- bf16 transpose: [b][n][d] -> [b][d][n] --------------------
__global__ __launch_bounds__(256) void transpose_kernel(
    const ushort* __restrict__ src, ushort* __restrict__ dst)
{
  __shared__ ushort tile[64][72];
  const int t   = threadIdx.x;
  const int bid = blockIdx.x;
  const int b   = bid >> 10;
  const int rem = bid & 1023;
  const int n0  = (rem >> 4) << 6;
  const int d0  = (rem & 15) << 6;
  const ushort* sb = src + ((size_t)b * NSEQ) * DIMD;
  ushort* db       = dst + ((size_t)b * DIMD) * NSEQ;

#pragma unroll
  for (int k = 0; k < 2; ++k) {
    int c = t + 256 * k;
    int r = c >> 3, scol = (c & 7) * 8;
    *(uint4*)&tile[r][scol] =
        *(const uint4*)(sb + (size_t)(n0 + r) * DIMD + d0 + scol);
  }
  __syncthreads();
#pragma unroll
  for (int k = 0; k < 2; ++k) {
    int c = t + 256 * k;
    int dr = c >> 3, ns = (c & 7) * 8;
    union { ushort u[8]; uint4 q; } tv;
#pragma unroll
    for (int i = 0; i < 8; ++i) tv.u[i] = tile[ns + i][dr];
    *(uint4*)(db + (size_t)(d0 + dr) * NSEQ + n0 + ns) = tv.q;
  }
}

// ================== shared GEMM building blocks =============================
__device__ __forceinline__ void stage_chunk(const ushort* __restrict__ g,
                                            int ld, char* l, int tid) {
  const int o0 = tid * 16;
  const int o1 = o0 + 8192;
  const int s0 = swz64(o0);
  const int s1 = swz64(o1);
  gload16(g + (size_t)(s0 >> 6) * ld + ((s0 & 63) >> 1), l + o0);
  gload16(g + (size_t)(s1 >> 6) * ld + ((s1 & 63) >> 1), l + o1);
}

// linear stage: global already holds the swizzled 16KB chunk image
__device__ __forceinline__ void stage_lin(const ushort* __restrict__ g,
                                          char* l, int tid) {
  gload16(g + tid * 8,        l + tid * 16);
  gload16(g + 4096 + tid * 8, l + tid * 16 + 8192);
}

__device__ __forceinline__ bf16x8 ldsw_read(const char* base, int row, int lg) {
  return *(const bf16x8*)(base + swz64(row * 64 + lg * 16));
}

__device__ __forceinline__ void read_af(const char* Ac, int wm, int mh,
                                        int l15, int lg, bf16x8 (&af)[4]) {
#pragma unroll
  for (int m = 0; m < 4; ++m)
    af[m] = ldsw_read(Ac, wm * 128 + (mh * 4 + m) * 16 + l15, lg);
}
__device__ __forceinline__ void read_bf(const char* Bc, int wn,
                                        int l15, int lg, bf16x8 (&bf)[4]) {
#pragma unroll
  for (int n = 0; n < 4; ++n)
    bf[n] = ldsw_read(Bc, wn * 64 + n * 16 + l15, lg);
}

#define MFMA16(BASE)                                                          \
  do {                                                                        \
    MIDBAR();                                                                 \
    __builtin_amdgcn_s_setprio(1);                                            \
    _Pragma("unroll")                                                         \
    for (int m = 0; m < 4; ++m)                                               \
      _Pragma("unroll")                                                       \
      for (int n = 0; n < 4; ++n)                                             \
        acc[(BASE) + m][n] = __builtin_amdgcn_mfma_f32_16x16x32_bf16(         \
            af[m], bf[n], acc[(BASE) + m][n], 0, 0, 0);                       \
    __builtin_amdgcn_s_setprio(0);                                            \
  } while (0)

// ---- Core A (round-5 verified schedule; best measured for both GEMMs).
// BK=64 as 2 k-half chunks of [256 r][32 c] (16KB each), 128KB LDS dbuf.
// LINB: B operand blocked-linear (16384-elem tile stride, linear stage). ----
template <bool LINB>
__device__ __forceinline__ void gemm_core_A(
    const ushort* __restrict__ Ab, const ushort* __restrict__ Bb,
    int lda, int ldb, int NT, char* smem, f32x4 (&acc)[8][4],
    int tid, int wm, int wn, int l15, int lg)
{
  stage_chunk(Ab, lda, smem + 0, tid);
  if (LINB) stage_lin(Bb, smem + 32768, tid);
  else      stage_chunk(Bb, ldb, smem + 32768, tid);
  stage_chunk(Ab + 32, lda, smem + 16384, tid);
  if (LINB) stage_lin(Bb + 8192, smem + 49152, tid);
  else      stage_chunk(Bb + 32, ldb, smem + 49152, tid);
  ENDBARV4();

  for (int kt = 0; kt < NT; ++kt) {
    char* cb = smem + (kt & 1) * 65536;
    char* nbuf = smem + (((kt & 1) ^ 1) * 65536);
    const ushort* An = Ab + (size_t)(kt + 1) * 64;
    const ushort* Bn = LINB ? (Bb + (size_t)(kt + 1) * 16384)
                            : (Bb + (size_t)(kt + 1) * 64);
    const bool pf = (kt + 1 < NT);
    bf16x8 af[4], bf[4];

    read_af(cb + 0, wm, 0, l15, lg, af);
    read_bf(cb + 32768, wn, l15, lg, bf);
    if (pf) stage_chunk(An, lda, nbuf + 0, tid);
    MFMA16(0);
    ENDBAR();

    read_af(cb + 0, wm, 1, l15, lg, af);
    if (pf) {
      if (LINB) stage_lin(Bn, nbuf + 32768, tid);
      else      stage_chunk(Bn, ldb, nbuf + 32768, tid);
    }
    MFMA16(4);
    if (pf) { ENDBARV4(); } else { ENDBARV0(); }

    read_af(cb + 16384, wm, 0, l15, lg, af);
    read_bf(cb + 49152, wn, l15, lg, bf);
    if (pf) stage_chunk(An + 32, lda, nbuf + 16384, tid);
    MFMA16(0);
    ENDBAR();

    read_af(cb + 16384, wm, 1, l15, lg, af);
    if (pf) {
      if (LINB) stage_lin(Bn + 8192, nbuf + 49152, tid);
      else      stage_chunk(Bn + 32, ldb, nbuf + 49152, tid);
    }
    MFMA16(4);
    if (pf) { ENDBARV4(); } else { ENDBAR(); }
  }
}

// GEMM1: S = exp2(Q'.K^T) (log2e/32 folded into Q), BLOCKED S layout:
// [batch][by 0..15][kt 0..63][half 0..1][16KB swizzled chunk image].
// Each block: 256 v-rows (by) x 1024 t (bxx quarter) as 4 sequential 256x256
// sub-tiles (prologue/flush/atomics amortized 4x; NT flush overlaps next
// sub-tile's K-loop). Best-measured gemm1 variant (round 10, 306 us).
__global__ __launch_bounds__(512, 2) void gemm1_256(
    const ushort* __restrict__ Q, const ushort* __restrict__ K,
    ushort* __restrict__ S, float* __restrict__ Rsum,
    int b0, size_t s_stride)
{
  extern __shared__ char smem[];
  const int tid  = threadIdx.x;
  const int lane = tid & 63;
  const int wave = tid >> 6;
  const int wm = wave >> 2, wn = wave & 3;
  const int l15 = lane & 15, lg = lane >> 4;

  int by, bxx, bzc;
  if (gridDim.x == 8 * 64) {
    const int hw = blockIdx.x;
    bzc = hw & 7;                  // batch -> XCD
    const int inner = hw >> 3;     // 0..63
    by = inner & 15;
    bxx = inner >> 4;              // 0..3
  } else {
    by = blockIdx.y; bxx = blockIdx.x; bzc = 0;
  }

  const int bz   = b0 + bzc;
  const int row0 = by * 256;                       // v rows
  const ushort* Qb = Q + (size_t)bz * NSEQ * DIMD + (size_t)row0 * DIMD;
  const ushort* Kb0 = K + (size_t)bz * NSEQ * DIMD;

  float vsum[4] = {0.f, 0.f, 0.f, 0.f};

#pragma unroll 1
  for (int st = 0; st < 4; ++st) {
    const int bx = bxx * 4 + st;                   // 256-wide t tile index
    const ushort* Kb = Kb0 + (size_t)(bx * 256) * DIMD;

    f32x4 acc[8][4];
#pragma unroll
    for (int m = 0; m < 8; ++m)
#pragma unroll
      for (int n = 0; n < 4; ++n) acc[m][n] = 0.0f;

    // swapped: A-role (C rows = t) = K tile; B-role (C cols = v) = Q tile
    gemm_core_A<false>(Kb, Qb, DIMD, DIMD, DIMD / 64, smem, acc,
                       tid, wm, wn, l15, lg);

    // ---- epilogue: p = exp2(s'), build S-tile image in LDS ----
#pragma unroll
    for (int ti = 0; ti < 8; ++ti) {
      const int tl   = wm * 128 + ti * 16 + lg * 4;
      const int ktl  = tl >> 6;
      const int half = (tl >> 5) & 1;
      const int tcol = tl & 31;
      char* img = smem + (ktl * 2 + half) * 16384;
#pragma unroll
      for (int vi = 0; vi < 4; ++vi) {
        const int vrow = wn * 64 + vi * 16 + l15;
        float p0 = fexp2(acc[ti][vi][0]);
        float p1 = fexp2(acc[ti][vi][1]);
        float p2 = fexp2(acc[ti][vi][2]);
        float p3 = fexp2(acc[ti][vi][3]);
        vsum[vi] += (p0 + p1) + (p2 + p3);
        unsigned long long pk =
            (unsigned long long)f2bf(p0)        |
            ((unsigned long long)f2bf(p1) << 16) |
            ((unsigned long long)f2bf(p2) << 32) |
            ((unsigned long long)f2bf(p3) << 48);
        *(unsigned long long*)(img + swz64(vrow * 64 + tcol * 2)) = pk;
      }
    }
    __syncthreads();   // image complete

    // linear NT flush of the 128KB tile image
    ushort* region = S + (size_t)bzc * s_stride
                   + (size_t)by * 1048576 + (size_t)bx * 65536;
#pragma unroll
    for (int j = 0; j < 16; ++j) {
      const int off = (j * 512 + tid) * 16;
      u32x4 vle = *(const u32x4*)(smem + off);
      __builtin_nontemporal_store(vle, (u32x4*)((char*)region + off));
    }
    __syncthreads();   // all waves' LDS flush-reads retired -> safe to restage
  }

  float* Rs = Rsum + (size_t)bz * NSEQ;
#pragma unroll
  for (int vi = 0; vi < 4; ++vi) {
    float s = vsum[vi];
    s += __shfl_xor(s, 16, 64);
    s += __shfl_xor(s, 32, 64);
    if (lg == 0)
      atomicAdd(Rs + row0 + wn * 64 + vi * 16 + l15, s);
  }
}

// GEMM2: O = (S.V)/Rsum stored [v][d]. A-role = Vt (swizzle-staged);
// B-role = S in blocked layout (linear stage). Plain O stores (L2 merge).
__global__ __launch_bounds__(512, 2) void gemm2_256(
    const ushort* __restrict__ S, const ushort* __restrict__ Kt,
    const float* __restrict__ Rsum, float* __restrict__ Out,
    int b0, size_t s_stride)
{
  extern __shared__ char smem[];
  const int tid  = threadIdx.x;
  const int lane = tid & 63;
  const int wave = tid >> 6;
  const int wm = wave >> 2, wn = wave & 3;
  const int l15 = lane & 15, lg = lane >> 4;

  int bx, by, bzc;
  if (gridDim.z == BATCH) {
    const int hw = blockIdx.x + (blockIdx.y << 2) + (blockIdx.z << 6);
    bzc = hw & 7;
    const int inner = hw >> 3;
    bx = inner & 3; by = inner >> 2;
  } else {
    bx = blockIdx.x; by = blockIdx.y; bzc = 0;
  }

  const int bz   = b0 + bzc;
  const int row0 = by * 256;   // v rows
  const int col0 = bx * 256;   // d cols
  const ushort* Sbase = S + (size_t)bzc * s_stride + (size_t)by * 1048576;
  const ushort* Vtb = Kt + ((size_t)bz * DIMD + col0) * NSEQ;

  f32x4 acc[8][4];
#pragma unroll
  for (int m = 0; m < 8; ++m)
#pragma unroll
    for (int n = 0; n < 4; ++n) acc[m][n] = 0.0f;

  // swapped: A-role (C rows = d) = Vt tile; B-role (C cols = v) = blocked S
  gemm_core_A<true>(Vtb, Sbase, NSEQ, 0, NSEQ / 64, smem, acc, tid, wm, wn, l15, lg);

  const float* Rs = Rsum + (size_t)bz * NSEQ;
  float* Ob = Out + (size_t)bz * NSEQ * DIMD;
  float inv[4];
#pragma unroll
  for (int vi = 0; vi < 4; ++vi)
    inv[vi] = 1.0f / Rs[row0 + wn * 64 + vi * 16 + l15];
#pragma unroll
  for (int di = 0; di < 8; ++di) {
#pragma unroll
    for (int vi = 0; vi < 4; ++vi) {
      const int v = row0 + wn * 64 + vi * 16 + l15;
      const int d = col0 + wm * 128 + di * 16 + lg * 4;
      f32x4 o = acc[di][vi] * inv[vi];
      *(f32x4*)(Ob + (size_t)v * DIMD + d) = o;
    }
  }
}

extern "C" void kernel_launch(void* const* d_in, const int* in_sizes, int n_in,
                              void* d_out, int out_size, void* d_ws, size_t ws_size,
                              hipStream_t stream) {
  const float* vis = (const float*)d_in[0];
  const float* txt = (const float*)d_in[1];
  const float* gv  = (const float*)d_in[2];
  const float* bv  = (const float*)d_in[3];
  const float* gt  = (const float*)d_in[4];
  const float* bt  = (const float*)d_in[5];
  float* out = (float*)d_out;

  const size_t tokens = (size_t)BATCH * NSEQ * DIMD;      // 33,554,432 elems
  ushort* Qbf = (ushort*)d_ws;                            // 64 MiB
  ushort* Kbf = Qbf + tokens;                             // 64 MiB
  ushort* Ktb = Kbf + tokens;                             // 64 MiB
  char*   wsb = (char*)d_ws;
  float*  Rsum = (float*)(wsb + 201326592);               // @192 MiB
  ushort* Sbuf = (ushort*)(wsb + 201457664);              // S region (blocked)

  const size_t S_FULL = (size_t)BATCH * NSEQ * NSEQ * 2;  // 256 MiB
  const size_t NEED_FULL = 201457664 + S_FULL;

  // fused dual LN: visual gets (1/sqrt(1024))*log2(e) folded in (exp2 domain)
  ln2_bf16_kernel<<<2 * BATCH * NSEQ / 4, 256, 0, stream>>>(
      vis, gv, bv, Qbf, txt, gt, bt, Kbf);
  transpose_kernel<<<BATCH * (NSEQ / 64) * (DIMD / 64), 256, 0, stream>>>(Kbf, Ktb);

  (void)hipFuncSetAttribute((const void*)gemm1_256,
                      hipFuncAttributeMaxDynamicSharedMemorySize, 131072);
  (void)hipFuncSetAttribute((const void*)gemm2_256,
                      hipFuncAttributeMaxDynamicSharedMemorySize, 131072);

  (void)hipMemsetAsync(Rsum, 0, (size_t)BATCH * NSEQ * sizeof(float), stream);

  if (ws_size >= NEED_FULL) {
    gemm1_256<<<dim3(8 * 64, 1, 1), 512, 131072, stream>>>(
        Qbf, Kbf, Sbuf, Rsum, 0, (size_t)NSEQ * NSEQ);
    gemm2_256<<<dim3(4, 16, BATCH), 512, 131072, stream>>>(
        Sbuf, Ktb, Rsum, out, 0, (size_t)NSEQ * NSEQ);
  } else {
    for (int b = 0; b < BATCH; ++b) {
      gemm1_256<<<dim3(4, 16, 1), 512, 131072, stream>>>(
          Qbf, Kbf, Sbuf, Rsum, b, 0);
      gemm2_256<<<dim3(4, 16, 1), 512, 131072, stream>>>(
          Sbuf, Ktb, Rsum, out, b, 0);
    }
  }
}